// Round 1
// baseline (4629.130 us; speedup 1.0000x reference)
//
#include <hip/hip_runtime.h>
#include <stdint.h>

typedef unsigned short u16;
typedef __attribute__((ext_vector_type(8))) short bf16x8;
typedef __attribute__((ext_vector_type(4))) float fx4;

#define MFMA16(a, b, c) __builtin_amdgcn_mfma_f32_16x16x32_bf16((a), (b), (c), 0, 0, 0)

// problem dims
#define NB 256
#define NL 512
#define NIN 64
#define NU 256
#define NSTEPS 64
#define NOUT 32

// ---- workspace layout (bytes) ----
#define OFF_X      0u           // x bf16 [B][L][256]           67108864
#define OFF_SEQ    67108864u    // enc hidden bf16 [B][L][256]  67108864
#define OFF_FSEQ   134217728u   // dec hidden bf16 [B][64][256]  8388608
#define OFF_ENCWT  142606336u   // enc_W^T bf16 [1024][256]       524288
#define OFF_ENCUT  143130624u   // enc_U^T bf16 [1024][256]       524288
#define OFF_CELLT  143654912u   // (cell_W+cell_U)^T bf16         524288
#define OFF_CONVKT 144179200u   // conv k^T bf16 [256][320]       163840
#define OFF_BWT    144343040u   // back_W^T bf16 [64][256]         32768
#define OFF_FWT    144375808u   // fore_W^T bf16 [32][256]         16384
#define OFF_HBUF   144392192u   // h exchange [16][2][16][256]bf16 262144
#define OFF_BAR    144654336u   // 16 barrier counters, 64B apart   1024

__device__ __forceinline__ u16 f2bf(float f) {
    uint32_t u = __builtin_bit_cast(uint32_t, f);
    u += 0x7FFFu + ((u >> 16) & 1u);   // RNE
    return (u16)(u >> 16);
}

__device__ __forceinline__ float sigm(float x) { return 1.0f / (1.0f + __expf(-x)); }
// safe tanh: no inf/inf NaN at extremes
__device__ __forceinline__ float tanh_f(float x) { return 1.0f - 2.0f / (__expf(2.0f * x) + 1.0f); }

// ---------------------------------------------------------------------------
// zero hbuf + barrier counters (ws is poisoned 0xAA before every timed call)
__global__ void zero_kernel(unsigned char* ws) {
    uint32_t* p = (uint32_t*)(ws + OFF_HBUF);
    const int n = (262144 + 1024) / 4;
    for (int i = blockIdx.x * blockDim.x + threadIdx.x; i < n; i += gridDim.x * blockDim.x)
        p[i] = 0u;
}

// ---------------------------------------------------------------------------
// transpose + bf16-convert all weight matrices
__global__ void prep_kernel(const float* enc_W, const float* enc_U, const float* cell_W,
                            const float* cell_U, const float* conv_k, const float* back_W,
                            const float* fore_W, unsigned char* ws) {
    u16* encWt = (u16*)(ws + OFF_ENCWT);
    u16* encUt = (u16*)(ws + OFF_ENCUT);
    u16* cellT = (u16*)(ws + OFF_CELLT);
    u16* convKt = (u16*)(ws + OFF_CONVKT);
    u16* bwt = (u16*)(ws + OFF_BWT);
    u16* fwt = (u16*)(ws + OFF_FWT);
    int idx = blockIdx.x * blockDim.x + threadIdx.x;
    int stride = gridDim.x * blockDim.x;
    // [n][k] = src[k][n], n<1024, k<256
    for (int i = idx; i < 262144; i += stride) {
        int n = i >> 8, k = i & 255;
        encWt[i] = f2bf(enc_W[k * 1024 + n]);
        encUt[i] = f2bf(enc_U[k * 1024 + n]);
        cellT[i] = f2bf(cell_W[k * 1024 + n] + cell_U[k * 1024 + n]);
    }
    // convKt[u][kk*64+c] = conv_k[kk][c][u]   (conv_k is [5][64][256])
    for (int i = idx; i < 81920; i += stride) {
        int u = i / 320, rem = i - u * 320;
        convKt[i] = f2bf(conv_k[rem * 256 + u]);
    }
    for (int i = idx; i < 16384; i += stride) {
        int n = i >> 8, k = i & 255;
        bwt[i] = f2bf(back_W[k * 64 + n]);
    }
    for (int i = idx; i < 8192; i += stride) {
        int n = i >> 8, k = i & 255;
        fwt[i] = f2bf(fore_W[k * 32 + n]);
    }
}

// ---------------------------------------------------------------------------
// Conv1D(same,k=5)+bias+ReLU as MFMA GEMM: A = im2col(inputs) [BL x 320],
// B = convKt [320 x 256]. Each wave: one 16-row M-tile over all 16 N-tiles.
__global__ __launch_bounds__(256) void conv_kernel(const float* __restrict__ in,
                                                   const float* __restrict__ conv_b,
                                                   unsigned char* ws) {
    const u16* kt = (const u16*)(ws + OFF_CONVKT);
    u16* xout = (u16*)(ws + OFF_X);
    int w = threadIdx.x >> 6, lane = threadIdx.x & 63;
    int m = lane & 15, q = lane >> 4;
    int mt = blockIdx.x * 4 + w;       // 0..8191
    int r0 = mt * 16;
    int b = r0 >> 9;
    int l0 = r0 & 511;

    fx4 acc[16];
#pragma unroll
    for (int nt = 0; nt < 16; ++nt) acc[nt] = (fx4){0.f, 0.f, 0.f, 0.f};

#pragma unroll
    for (int s = 0; s < 10; ++s) {
        int k0 = s * 32 + q * 8;
        int kk = k0 >> 6, c = k0 & 63;
        int l2 = l0 + m + kk - 2;
        bf16x8 af = {0, 0, 0, 0, 0, 0, 0, 0};
        if (l2 >= 0 && l2 < 512) {
            const float* src = in + (((b << 9) + l2) << 6) + c;
            fx4 f0 = *(const fx4*)src;
            fx4 f1 = *(const fx4*)(src + 4);
            af[0] = (short)f2bf(f0[0]); af[1] = (short)f2bf(f0[1]);
            af[2] = (short)f2bf(f0[2]); af[3] = (short)f2bf(f0[3]);
            af[4] = (short)f2bf(f1[0]); af[5] = (short)f2bf(f1[1]);
            af[6] = (short)f2bf(f1[2]); af[7] = (short)f2bf(f1[3]);
        }
#pragma unroll
        for (int nt = 0; nt < 16; ++nt) {
            bf16x8 bf = *(const bf16x8*)(kt + (nt * 16 + m) * 320 + k0);
            acc[nt] = MFMA16(af, bf, acc[nt]);
        }
    }
#pragma unroll
    for (int nt = 0; nt < 16; ++nt) {
        int u = nt * 16 + m;
        float bias = conv_b[u];
#pragma unroll
        for (int r = 0; r < 4; ++r) {
            float v = acc[nt][r] + bias;
            v = v > 0.f ? v : 0.f;
            int row = r0 + q * 4 + r;
            xout[row * 256 + u] = f2bf(v);
        }
    }
}

// ---------------------------------------------------------------------------
// Fused encoder (512 steps) + decoder (64 steps) LSTM.
// Grid: 64 WGs = 16 batch-groups x 4 members. group g = bid&15 (16 batch rows),
// member p = bid>>4 owns hidden units [p*64, p*64+64). Wave w owns the 16-unit
// tile un0 = p*64+w*16 and keeps W/U B-fragments for all 4 gates in VGPRs.
// h exchanged per step via double-buffered global buffer + per-group barrier.
__global__ __launch_bounds__(256, 1) void encdec_kernel(const float* __restrict__ enc_b,
                                                        const float* __restrict__ cell_b,
                                                        unsigned char* ws) {
    int tid = threadIdx.x;
    int w = tid >> 6, lane = tid & 63, m = lane & 15, q = lane >> 4;
    int bid = blockIdx.x;
    int g = bid & 15, p = bid >> 4;   // members {g, g+16, g+32, g+48} share an XCD (heuristic)
    int b0 = g * 16;
    int un0 = p * 64 + w * 16;

    const u16* encWt = (const u16*)(ws + OFF_ENCWT);
    const u16* encUt = (const u16*)(ws + OFF_ENCUT);
    const u16* cellT = (const u16*)(ws + OFF_CELLT);
    const u16* xbf = (const u16*)(ws + OFF_X);
    u16* seq = (u16*)(ws + OFF_SEQ);
    u16* fseq = (u16*)(ws + OFF_FSEQ);
    u16* hbuf = (u16*)(ws + OFF_HBUF);
    int* bar_g = (int*)(ws + OFF_BAR + g * 64);

    bf16x8 wfrag[4][8], ufrag[4][8];
#pragma unroll
    for (int gi = 0; gi < 4; ++gi) {
#pragma unroll
        for (int s = 0; s < 8; ++s) {
            int n = gi * 256 + un0 + m;
            wfrag[gi][s] = *(const bf16x8*)(encWt + n * 256 + s * 32 + q * 8);
            ufrag[gi][s] = *(const bf16x8*)(encUt + n * 256 + s * 32 + q * 8);
        }
    }
    float bi[4], creg[4];
#pragma unroll
    for (int gi = 0; gi < 4; ++gi) bi[gi] = enc_b[gi * 256 + un0 + m];
    creg[0] = creg[1] = creg[2] = creg[3] = 0.f;

    u16* hb_g = hbuf + g * 8192;                         // [2][16][256]
    const u16* xrowbase = xbf + (b0 + m) * (512 * 256) + q * 8;

    for (int t = 0; t < 576; ++t) {
        int rt = t & 1;
        const u16* hA = hb_g + rt * 4096 + m * 256 + q * 8;
        u16* hW = hb_g + (rt ^ 1) * 4096;

        bf16x8 ha[8];
#pragma unroll
        for (int s = 0; s < 8; ++s) ha[s] = *(const bf16x8*)(hA + s * 32);

        fx4 acc[4];
        if (t < 512) {
            const u16* xA = xrowbase + t * 256;
            bf16x8 xa[8];
#pragma unroll
            for (int s = 0; s < 8; ++s) xa[s] = *(const bf16x8*)(xA + s * 32);
#pragma unroll
            for (int gi = 0; gi < 4; ++gi) acc[gi] = (fx4){bi[gi], bi[gi], bi[gi], bi[gi]};
#pragma unroll
            for (int s = 0; s < 8; ++s) {
#pragma unroll
                for (int gi = 0; gi < 4; ++gi) {
                    acc[gi] = MFMA16(xa[s], wfrag[gi][s], acc[gi]);
                    acc[gi] = MFMA16(ha[s], ufrag[gi][s], acc[gi]);
                }
            }
        } else {
#pragma unroll
            for (int gi = 0; gi < 4; ++gi) acc[gi] = (fx4){bi[gi], bi[gi], bi[gi], bi[gi]};
#pragma unroll
            for (int s = 0; s < 8; ++s) {
#pragma unroll
                for (int gi = 0; gi < 4; ++gi)
                    acc[gi] = MFMA16(ha[s], wfrag[gi][s], acc[gi]);
            }
        }

        // gates: i=acc[0], f=acc[1], g=acc[2], o=acc[3]; rows q*4+r, unit un0+m
#pragma unroll
        for (int r = 0; r < 4; ++r) {
            float cv = sigm(acc[1][r]) * creg[r] + sigm(acc[0][r]) * tanh_f(acc[2][r]);
            creg[r] = cv;
            float hv = sigm(acc[3][r]) * tanh_f(cv);
            u16 hb = f2bf(hv);
            int row = q * 4 + r;
            int u = un0 + m;
            hW[row * 256 + u] = hb;
            if (t < 512) seq[((b0 + row) * 512 + t) * 256 + u] = hb;
            else         fseq[((b0 + row) * 64 + (t - 512)) * 256 + u] = hb;
        }

        if (t == 511) {   // switch to decoder weights (combined cell_W+cell_U)
#pragma unroll
            for (int gi = 0; gi < 4; ++gi) {
#pragma unroll
                for (int s = 0; s < 8; ++s)
                    wfrag[gi][s] = *(const bf16x8*)(cellT + (gi * 256 + un0 + m) * 256 + s * 32 + q * 8);
            }
#pragma unroll
            for (int gi = 0; gi < 4; ++gi) bi[gi] = cell_b[gi * 256 + un0 + m];
        }

        // per-group barrier (device-scope; correct regardless of XCD placement)
        __syncthreads();
        if (tid == 0) {
            __threadfence();   // release: push h-slice stores past L2
            __hip_atomic_fetch_add(bar_g, 1, __ATOMIC_RELAXED, __HIP_MEMORY_SCOPE_AGENT);
            int target = 4 * (t + 1);
            while (__hip_atomic_load(bar_g, __ATOMIC_RELAXED, __HIP_MEMORY_SCOPE_AGENT) < target) {
                __builtin_amdgcn_s_sleep(2);
            }
        }
        __syncthreads();
        __threadfence();       // acquire: invalidate stale L1/L2 before reading peers' h
    }
}

// ---------------------------------------------------------------------------
// out[r][n] = A[r][:] @ Bt[n][:] + bias[n];  A bf16 [rows][256], Bt bf16 [ncols][256]
__global__ __launch_bounds__(256) void out_gemm(const u16* __restrict__ A,
                                                const u16* __restrict__ Bt,
                                                const float* __restrict__ bias,
                                                float* __restrict__ out, int ncols) {
    int w = threadIdx.x >> 6, lane = threadIdx.x & 63, m = lane & 15, q = lane >> 4;
    int mt = blockIdx.x * 4 + w;
    bf16x8 af[8];
#pragma unroll
    for (int s = 0; s < 8; ++s)
        af[s] = *(const bf16x8*)(A + (mt * 16 + m) * 256 + s * 32 + q * 8);
    int ntiles = ncols >> 4;
    for (int nt = 0; nt < ntiles; ++nt) {
        fx4 acc = (fx4){0.f, 0.f, 0.f, 0.f};
#pragma unroll
        for (int s = 0; s < 8; ++s) {
            bf16x8 bf = *(const bf16x8*)(Bt + (nt * 16 + m) * 256 + s * 32 + q * 8);
            acc = MFMA16(af[s], bf, acc);
        }
        int col = nt * 16 + m;
        float bv = bias[col];
#pragma unroll
        for (int r = 0; r < 4; ++r) {
            int row = mt * 16 + q * 4 + r;
            out[row * ncols + col] = acc[r] + bv;
        }
    }
}

// ---------------------------------------------------------------------------
extern "C" void kernel_launch(void* const* d_in, const int* in_sizes, int n_in,
                              void* d_out, int out_size, void* d_ws, size_t ws_size,
                              hipStream_t stream) {
    const float* inputs = (const float*)d_in[0];
    const float* conv_k = (const float*)d_in[1];
    const float* conv_b = (const float*)d_in[2];
    const float* enc_W  = (const float*)d_in[3];
    const float* enc_U  = (const float*)d_in[4];
    const float* enc_b  = (const float*)d_in[5];
    const float* cell_W = (const float*)d_in[6];
    const float* cell_U = (const float*)d_in[7];
    const float* cell_b = (const float*)d_in[8];
    const float* fore_W = (const float*)d_in[9];
    const float* fore_b = (const float*)d_in[10];
    const float* back_W = (const float*)d_in[11];
    const float* back_b = (const float*)d_in[12];
    unsigned char* ws = (unsigned char*)d_ws;
    float* out = (float*)d_out;

    // NOTE: requires ws_size >= ~144.7 MB (OFF_BAR + 1024)

    zero_kernel<<<64, 256, 0, stream>>>(ws);
    prep_kernel<<<1024, 256, 0, stream>>>(enc_W, enc_U, cell_W, cell_U, conv_k, back_W, fore_W, ws);
    conv_kernel<<<2048, 256, 0, stream>>>(inputs, conv_b, ws);
    encdec_kernel<<<64, 256, 0, stream>>>(enc_b, cell_b, ws);
    // backcast: [B*L, 256] @ [256,64] -> d_out + 524288
    out_gemm<<<2048, 256, 0, stream>>>((const u16*)(ws + OFF_SEQ), (const u16*)(ws + OFF_BWT),
                                       back_b, out + 524288, 64);
    // forecast: [B*64, 256] @ [256,32] -> d_out
    out_gemm<<<256, 256, 0, stream>>>((const u16*)(ws + OFF_FSEQ), (const u16*)(ws + OFF_FWT),
                                      fore_b, out, 32);
}

// Round 2
// 2755.543 us; speedup vs baseline: 1.6799x; 1.6799x over previous
//
#include <hip/hip_runtime.h>
#include <stdint.h>

typedef unsigned short u16;
typedef __attribute__((ext_vector_type(8))) short bf16x8;
typedef __attribute__((ext_vector_type(4))) float fx4;

#define MFMA16(a, b, c) __builtin_amdgcn_mfma_f32_16x16x32_bf16((a), (b), (c), 0, 0, 0)

// ---- workspace layout (bytes) ----
// X is dead after enc_kernel finishes; CSAVE (256*256*4 = 262144 B) overlays
// X[b=0] (exactly 512*256*2 B), which is only read by group 0's own waves —
// group 0 writes CSAVE only after finishing all its X reads. Safe.
#define OFF_X      0u            // x bf16 [B][L][256]             67108864
#define OFF_CSAVE  0u            // c fp32 [256][256] (overlays X)
#define OFF_H      67108864u     // H bf16 [577][256][256] rotating 75628544
#define OFF_ENCWT  142737408u    // enc_W^T bf16 [1024][256]         524288
#define OFF_ENCUT  143261696u    // enc_U^T bf16 [1024][256]         524288
#define OFF_CELLT  143785984u    // (cell_W+cell_U)^T bf16           524288
#define OFF_CONVKT 144310272u    // conv k^T bf16 [256][320]         163840
#define OFF_BWT    144474112u    // back_W^T bf16 [64][256]           32768
#define OFF_FWT    144506880u    // fore_W^T bf16 [32][256]           16384
#define OFF_BAR    144523264u    // 16 barrier counters, 64B apart     1024
// end: 144524288 bytes (less than round-1's working requirement)

__device__ __forceinline__ u16 f2bf(float f) {
    uint32_t u = __builtin_bit_cast(uint32_t, f);
    u += 0x7FFFu + ((u >> 16) & 1u);   // RNE
    return (u16)(u >> 16);
}
__device__ __forceinline__ float sigm(float x) { return 1.0f / (1.0f + __expf(-x)); }
__device__ __forceinline__ float tanh_f(float x) { return 1.0f - 2.0f / (__expf(2.0f * x) + 1.0f); }

// store 2 bytes bypassing L1/L2 -> lands at device-coherent point (L3)
__device__ __forceinline__ void store_h_sc(const u16* p, uint32_t v) {
    asm volatile("global_store_short %0, %1, off sc0 sc1" :: "v"(p), "v"(v) : "memory");
}
// drain all vector-memory ops (incl. the asm sc stores the compiler can't see)
__device__ __forceinline__ void vmcnt0() { asm volatile("s_waitcnt vmcnt(0)" ::: "memory"); }

// ---------------------------------------------------------------------------
__global__ void zero_kernel(unsigned char* ws) {
    int i = blockIdx.x * blockDim.x + threadIdx.x;   // 16384 threads
    uint32_t* h0 = (uint32_t*)(ws + OFF_H);          // slot 0: 131072 B
    for (int k = i; k < 32768; k += 16384) h0[k] = 0u;
    if (i < 256) ((uint32_t*)(ws + OFF_BAR))[i] = 0u;
}

// ---------------------------------------------------------------------------
__global__ void prep_kernel(const float* enc_W, const float* enc_U, const float* cell_W,
                            const float* cell_U, const float* conv_k, const float* back_W,
                            const float* fore_W, unsigned char* ws) {
    u16* encWt = (u16*)(ws + OFF_ENCWT);
    u16* encUt = (u16*)(ws + OFF_ENCUT);
    u16* cellT = (u16*)(ws + OFF_CELLT);
    u16* convKt = (u16*)(ws + OFF_CONVKT);
    u16* bwt = (u16*)(ws + OFF_BWT);
    u16* fwt = (u16*)(ws + OFF_FWT);
    int idx = blockIdx.x * blockDim.x + threadIdx.x;
    int stride = gridDim.x * blockDim.x;
    for (int i = idx; i < 262144; i += stride) {
        int n = i >> 8, k = i & 255;
        encWt[i] = f2bf(enc_W[k * 1024 + n]);
        encUt[i] = f2bf(enc_U[k * 1024 + n]);
        cellT[i] = f2bf(cell_W[k * 1024 + n] + cell_U[k * 1024 + n]);
    }
    for (int i = idx; i < 81920; i += stride) {
        int u = i / 320, rem = i - u * 320;
        convKt[i] = f2bf(conv_k[rem * 256 + u]);
    }
    for (int i = idx; i < 16384; i += stride) {
        int n = i >> 8, k = i & 255;
        bwt[i] = f2bf(back_W[k * 64 + n]);
    }
    for (int i = idx; i < 8192; i += stride) {
        int n = i >> 8, k = i & 255;
        fwt[i] = f2bf(fore_W[k * 32 + n]);
    }
}

// ---------------------------------------------------------------------------
// Conv1D(same,k=5)+bias+ReLU as MFMA GEMM (unchanged from round 1)
__global__ __launch_bounds__(256) void conv_kernel(const float* __restrict__ in,
                                                   const float* __restrict__ conv_b,
                                                   unsigned char* ws) {
    const u16* kt = (const u16*)(ws + OFF_CONVKT);
    u16* xout = (u16*)(ws + OFF_X);
    int w = threadIdx.x >> 6, lane = threadIdx.x & 63;
    int m = lane & 15, q = lane >> 4;
    int mt = blockIdx.x * 4 + w;
    int r0 = mt * 16;
    int b = r0 >> 9;
    int l0 = r0 & 511;

    fx4 acc[16];
#pragma unroll
    for (int nt = 0; nt < 16; ++nt) acc[nt] = (fx4){0.f, 0.f, 0.f, 0.f};

#pragma unroll
    for (int s = 0; s < 10; ++s) {
        int k0 = s * 32 + q * 8;
        int kk = k0 >> 6, c = k0 & 63;
        int l2 = l0 + m + kk - 2;
        bf16x8 af = {0, 0, 0, 0, 0, 0, 0, 0};
        if (l2 >= 0 && l2 < 512) {
            const float* src = in + (((b << 9) + l2) << 6) + c;
            fx4 f0 = *(const fx4*)src;
            fx4 f1 = *(const fx4*)(src + 4);
            af[0] = (short)f2bf(f0[0]); af[1] = (short)f2bf(f0[1]);
            af[2] = (short)f2bf(f0[2]); af[3] = (short)f2bf(f0[3]);
            af[4] = (short)f2bf(f1[0]); af[5] = (short)f2bf(f1[1]);
            af[6] = (short)f2bf(f1[2]); af[7] = (short)f2bf(f1[3]);
        }
#pragma unroll
        for (int nt = 0; nt < 16; ++nt) {
            bf16x8 bf = *(const bf16x8*)(kt + (nt * 16 + m) * 320 + k0);
            acc[nt] = MFMA16(af, bf, acc[nt]);
        }
    }
#pragma unroll
    for (int nt = 0; nt < 16; ++nt) {
        int u = nt * 16 + m;
        float bias = conv_b[u];
#pragma unroll
        for (int r = 0; r < 4; ++r) {
            float v = acc[nt][r] + bias;
            v = v > 0.f ? v : 0.f;
            int row = r0 + q * 4 + r;
            xout[row * 256 + u] = f2bf(v);
        }
    }
}

// ---------------------------------------------------------------------------
// Encoder: 512 steps. 64 WGs = 16 groups (g=bid&15, 16 batch rows) x 4 members
// (p=bid>>4, 64 hidden units each). Wave w owns 16 units; W/U fragments in
// VGPRs. h exchange: sc0sc1 stores into rotating H[t] + relaxed agent atomics.
// No fences anywhere: exchange data lives at the device-coherent point, and
// peer reads hit never-before-cached lines (rotating buffer).
__global__ __launch_bounds__(256, 1) void enc_kernel(const float* __restrict__ enc_b,
                                                     unsigned char* ws) {
    int tid = threadIdx.x;
    int w = tid >> 6, lane = tid & 63, m = lane & 15, q = lane >> 4;
    int bid = blockIdx.x;
    int g = bid & 15, p = bid >> 4;
    int b0 = g * 16;
    int un0 = p * 64 + w * 16;

    const u16* encWt = (const u16*)(ws + OFF_ENCWT);
    const u16* encUt = (const u16*)(ws + OFF_ENCUT);
    const u16* xbf = (const u16*)(ws + OFF_X);
    u16* H = (u16*)(ws + OFF_H);
    float* csave = (float*)(ws + OFF_CSAVE);
    int* bar = (int*)(ws + OFF_BAR + g * 64);

    bf16x8 wfrag[4][8], ufrag[4][8];
#pragma unroll
    for (int gi = 0; gi < 4; ++gi) {
#pragma unroll
        for (int s = 0; s < 8; ++s) {
            int n = gi * 256 + un0 + m;
            wfrag[gi][s] = *(const bf16x8*)(encWt + n * 256 + s * 32 + q * 8);
            ufrag[gi][s] = *(const bf16x8*)(encUt + n * 256 + s * 32 + q * 8);
        }
    }
    float bi[4], creg[4];
#pragma unroll
    for (int gi = 0; gi < 4; ++gi) bi[gi] = enc_b[gi * 256 + un0 + m];
    creg[0] = creg[1] = creg[2] = creg[3] = 0.f;

    const u16* xrow = xbf + (size_t)(b0 + m) * (512 * 256) + q * 8;

    for (int t = 0; t < 512; ++t) {
        // ---- x part: independent of peers; overlaps their h-chain ----
        bf16x8 xa[8];
        const u16* xA = xrow + (size_t)t * 256;
#pragma unroll
        for (int s = 0; s < 8; ++s) xa[s] = *(const bf16x8*)(xA + s * 32);
        fx4 acc[4];
#pragma unroll
        for (int gi = 0; gi < 4; ++gi) acc[gi] = (fx4){bi[gi], bi[gi], bi[gi], bi[gi]};
#pragma unroll
        for (int s = 0; s < 8; ++s) {
#pragma unroll
            for (int gi = 0; gi < 4; ++gi)
                acc[gi] = MFMA16(xa[s], wfrag[gi][s], acc[gi]);
        }

        // ---- wait for all 16 group-waves to have finished step t-1 ----
        if (lane == 0) {
            int tgt = 4 * t;
            while (__hip_atomic_load(bar, __ATOMIC_RELAXED, __HIP_MEMORY_SCOPE_AGENT) < tgt) {}
        }
        asm volatile("" ::: "memory");   // don't hoist ha loads above the poll

        // ---- h part ----
        const u16* hA = H + (size_t)t * 65536 + (b0 + m) * 256 + q * 8;
        bf16x8 ha[8];
#pragma unroll
        for (int s = 0; s < 8; ++s) ha[s] = *(const bf16x8*)(hA + s * 32);
#pragma unroll
        for (int s = 0; s < 8; ++s) {
#pragma unroll
            for (int gi = 0; gi < 4; ++gi)
                acc[gi] = MFMA16(ha[s], ufrag[gi][s], acc[gi]);
        }

        // ---- gates + h store to slot t+1 (sc0 sc1: straight to L3) ----
        const u16* hw = H + (size_t)(t + 1) * 65536 + un0 + m;
#pragma unroll
        for (int r = 0; r < 4; ++r) {
            float cv = sigm(acc[1][r]) * creg[r] + sigm(acc[0][r]) * tanh_f(acc[2][r]);
            creg[r] = cv;
            float hv = sigm(acc[3][r]) * tanh_f(cv);
            store_h_sc(hw + (b0 + q * 4 + r) * 256, (uint32_t)f2bf(hv));
        }
        vmcnt0();          // stores device-visible before the signal
        __syncthreads();   // all 4 waves of this WG drained
        if (tid == 0)
            __hip_atomic_fetch_add(bar, 1, __ATOMIC_RELAXED, __HIP_MEMORY_SCOPE_AGENT);
    }

    // hand off c to the decoder (normal stores; kernel-end flush makes visible)
#pragma unroll
    for (int r = 0; r < 4; ++r)
        csave[(b0 + q * 4 + r) * 256 + un0 + m] = creg[r];
}

// ---------------------------------------------------------------------------
// Decoder: 64 steps, input = previous h, combined (cell_W+cell_U).
__global__ __launch_bounds__(256, 1) void dec_kernel(const float* __restrict__ cell_b,
                                                     unsigned char* ws) {
    int tid = threadIdx.x;
    int w = tid >> 6, lane = tid & 63, m = lane & 15, q = lane >> 4;
    int bid = blockIdx.x;
    int g = bid & 15, p = bid >> 4;
    int b0 = g * 16;
    int un0 = p * 64 + w * 16;

    const u16* cellT = (const u16*)(ws + OFF_CELLT);
    u16* H = (u16*)(ws + OFF_H);
    const float* csave = (const float*)(ws + OFF_CSAVE);
    int* bar = (int*)(ws + OFF_BAR + g * 64);

    bf16x8 wfrag[4][8];
#pragma unroll
    for (int gi = 0; gi < 4; ++gi) {
#pragma unroll
        for (int s = 0; s < 8; ++s)
            wfrag[gi][s] = *(const bf16x8*)(cellT + (gi * 256 + un0 + m) * 256 + s * 32 + q * 8);
    }
    float bi[4], creg[4];
#pragma unroll
    for (int gi = 0; gi < 4; ++gi) bi[gi] = cell_b[gi * 256 + un0 + m];
#pragma unroll
    for (int r = 0; r < 4; ++r) creg[r] = csave[(b0 + q * 4 + r) * 256 + un0 + m];

    for (int t = 0; t < 64; ++t) {
        if (lane == 0) {
            int tgt = 2048 + 4 * t;   // encoder left counter at 4*512 = 2048
            while (__hip_atomic_load(bar, __ATOMIC_RELAXED, __HIP_MEMORY_SCOPE_AGENT) < tgt) {}
        }
        asm volatile("" ::: "memory");

        const u16* hA = H + (size_t)(512 + t) * 65536 + (b0 + m) * 256 + q * 8;
        bf16x8 ha[8];
#pragma unroll
        for (int s = 0; s < 8; ++s) ha[s] = *(const bf16x8*)(hA + s * 32);
        fx4 acc[4];
#pragma unroll
        for (int gi = 0; gi < 4; ++gi) acc[gi] = (fx4){bi[gi], bi[gi], bi[gi], bi[gi]};
#pragma unroll
        for (int s = 0; s < 8; ++s) {
#pragma unroll
            for (int gi = 0; gi < 4; ++gi)
                acc[gi] = MFMA16(ha[s], wfrag[gi][s], acc[gi]);
        }

        const u16* hw = H + (size_t)(513 + t) * 65536 + un0 + m;
#pragma unroll
        for (int r = 0; r < 4; ++r) {
            float cv = sigm(acc[1][r]) * creg[r] + sigm(acc[0][r]) * tanh_f(acc[2][r]);
            creg[r] = cv;
            float hv = sigm(acc[3][r]) * tanh_f(cv);
            store_h_sc(hw + (b0 + q * 4 + r) * 256, (uint32_t)f2bf(hv));
        }
        vmcnt0();
        __syncthreads();
        if (tid == 0)
            __hip_atomic_fetch_add(bar, 1, __ATOMIC_RELAXED, __HIP_MEMORY_SCOPE_AGENT);
    }
}

// ---------------------------------------------------------------------------
// out[(b*seqlen+s)*ncols+col] = H-slot A[s][b][:] @ Bt[col][:] + bias[col]
__global__ __launch_bounds__(256) void out_gemm(const u16* __restrict__ A,
                                                const u16* __restrict__ Bt,
                                                const float* __restrict__ bias,
                                                float* __restrict__ out,
                                                int ncols, int seqlen) {
    int w = threadIdx.x >> 6, lane = threadIdx.x & 63, m = lane & 15, q = lane >> 4;
    int mt = blockIdx.x * 4 + w;
    int s = mt >> 4;
    int b0 = (mt & 15) * 16;
    bf16x8 af[8];
    const u16* Arow = A + ((size_t)s * 256 + b0 + m) * 256 + q * 8;
#pragma unroll
    for (int ss = 0; ss < 8; ++ss) af[ss] = *(const bf16x8*)(Arow + ss * 32);
    int ntiles = ncols >> 4;
    for (int nt = 0; nt < ntiles; ++nt) {
        fx4 acc = (fx4){0.f, 0.f, 0.f, 0.f};
#pragma unroll
        for (int ss = 0; ss < 8; ++ss) {
            bf16x8 bf = *(const bf16x8*)(Bt + (nt * 16 + m) * 256 + ss * 32 + q * 8);
            acc = MFMA16(af[ss], bf, acc);
        }
        int col = nt * 16 + m;
        float bv = bias[col];
#pragma unroll
        for (int r = 0; r < 4; ++r) {
            int b = b0 + q * 4 + r;
            out[((size_t)b * seqlen + s) * ncols + col] = acc[r] + bv;
        }
    }
}

// ---------------------------------------------------------------------------
extern "C" void kernel_launch(void* const* d_in, const int* in_sizes, int n_in,
                              void* d_out, int out_size, void* d_ws, size_t ws_size,
                              hipStream_t stream) {
    const float* inputs = (const float*)d_in[0];
    const float* conv_k = (const float*)d_in[1];
    const float* conv_b = (const float*)d_in[2];
    const float* enc_W  = (const float*)d_in[3];
    const float* enc_U  = (const float*)d_in[4];
    const float* enc_b  = (const float*)d_in[5];
    const float* cell_W = (const float*)d_in[6];
    const float* cell_U = (const float*)d_in[7];
    const float* cell_b = (const float*)d_in[8];
    const float* fore_W = (const float*)d_in[9];
    const float* fore_b = (const float*)d_in[10];
    const float* back_W = (const float*)d_in[11];
    const float* back_b = (const float*)d_in[12];
    unsigned char* ws = (unsigned char*)d_ws;
    float* out = (float*)d_out;

    zero_kernel<<<64, 256, 0, stream>>>(ws);
    prep_kernel<<<1024, 256, 0, stream>>>(enc_W, enc_U, cell_W, cell_U, conv_k, back_W, fore_W, ws);
    conv_kernel<<<2048, 256, 0, stream>>>(inputs, conv_b, ws);
    enc_kernel<<<64, 256, 0, stream>>>(enc_b, ws);
    dec_kernel<<<64, 256, 0, stream>>>(cell_b, ws);

    const u16* H = (const u16*)(ws + OFF_H);
    // backcast: slots 1..512 -> out[b][l][64] at float offset 524288
    out_gemm<<<2048, 256, 0, stream>>>(H + (size_t)1 * 65536, (const u16*)(ws + OFF_BWT),
                                       back_b, out + 524288, 64, 512);
    // forecast: slots 513..576 -> out[b][j][32]
    out_gemm<<<256, 256, 0, stream>>>(H + (size_t)513 * 65536, (const u16*)(ws + OFF_FWT),
                                      fore_b, out, 32, 64);
}